// Round 2
// baseline (771.515 us; speedup 1.0000x reference)
//
#include <hip/hip_runtime.h>
#include <hip/hip_bf16.h>
#include <hip/hip_fp16.h>
#include <cstdint>
#include <cstddef>

// Problem dims (fixed by reference): B=4 S=4096 H=2048 E=64 K=2
#define HH   2048
#define MM   16384
#define NE   64
#define LN_EPS  1e-5f
#define AUX_EPS 1e-9f

typedef __attribute__((ext_vector_type(8))) _Float16 f16x8;
typedef __attribute__((ext_vector_type(4))) _Float16 f16x4;
typedef __attribute__((ext_vector_type(4))) float    f32x4;

__device__ __forceinline__ void gload_lds16(const void* g, void* l) {
    __builtin_amdgcn_global_load_lds(
        (const __attribute__((address_space(1))) unsigned int*)g,
        (__attribute__((address_space(3))) unsigned int*)l,
        16, 0, 0);
}

// ---------------------------------------------------------------------------
// Kernel 1: W1 [K][N] f32 -> Wh [N][K] fp16 (hi), Wl [N][K] fp16 (lo * 2^10)
// ---------------------------------------------------------------------------
__global__ __launch_bounds__(256) void k_tw1(const float* __restrict__ W1,
                                             _Float16* __restrict__ Wh,
                                             _Float16* __restrict__ Wl) {
    __shared__ float tile[32][33];
    int tx = threadIdx.x & 31;
    int ty = threadIdx.x >> 5;          // 0..7
    int bx = blockIdx.x & 63;           // n-tile
    int by = blockIdx.x >> 6;           // k-tile
#pragma unroll
    for (int i = 0; i < 4; ++i) {
        int k = by * 32 + ty + i * 8;
        tile[ty + i * 8][tx] = W1[(size_t)k * HH + bx * 32 + tx];
    }
    __syncthreads();
#pragma unroll
    for (int i = 0; i < 4; ++i) {
        int n = bx * 32 + ty + i * 8;
        float w = tile[tx][ty + i * 8];
        _Float16 hi = (_Float16)w;
        _Float16 lo = (_Float16)((w - (float)hi) * 1024.0f);   // scaled to stay fp16-normal
        Wh[(size_t)n * HH + by * 32 + tx] = hi;
        Wl[(size_t)n * HH + by * 32 + tx] = lo;
    }
}

// ---------------------------------------------------------------------------
// Kernel 2: LayerNorm -> xh (fp16 hi), xl (fp16 lo, unscaled)
// ---------------------------------------------------------------------------
__global__ __launch_bounds__(256) void k_ln(const float* __restrict__ x,
                                            const float* __restrict__ gamma,
                                            const float* __restrict__ beta,
                                            _Float16* __restrict__ xh,
                                            _Float16* __restrict__ xl) {
    int row = blockIdx.x;
    int t = threadIdx.x;
    const float4* xr = (const float4*)(x + (size_t)row * HH);
    float4 v0 = xr[t];
    float4 v1 = xr[t + 256];
    float s  = v0.x + v0.y + v0.z + v0.w + v1.x + v1.y + v1.z + v1.w;
    float sq = v0.x*v0.x + v0.y*v0.y + v0.z*v0.z + v0.w*v0.w
             + v1.x*v1.x + v1.y*v1.y + v1.z*v1.z + v1.w*v1.w;
#pragma unroll
    for (int m = 1; m < 64; m <<= 1) { s += __shfl_xor(s, m); sq += __shfl_xor(sq, m); }
    __shared__ float red[8];
    int wv = t >> 6;
    if ((t & 63) == 0) { red[wv] = s; red[wv + 4] = sq; }
    __syncthreads();
    s  = red[0] + red[1] + red[2] + red[3];
    sq = red[4] + red[5] + red[6] + red[7];
    float mu  = s * (1.0f / HH);
    float var = sq * (1.0f / HH) - mu * mu;
    float rr  = rsqrtf(var + LN_EPS);

    const float4* gr = (const float4*)gamma;
    const float4* br = (const float4*)beta;
#pragma unroll
    for (int p = 0; p < 2; ++p) {
        int idx = t + p * 256;
        float4 v = (p == 0) ? v0 : v1;
        float4 g = gr[idx];
        float4 b = br[idx];
        float f[4];
        f[0] = (v.x - mu) * rr * g.x + b.x;
        f[1] = (v.y - mu) * rr * g.y + b.y;
        f[2] = (v.z - mu) * rr * g.z + b.z;
        f[3] = (v.w - mu) * rr * g.w + b.w;
        f16x4 oh, ol;
#pragma unroll
        for (int j = 0; j < 4; ++j) {
            _Float16 hi = (_Float16)f[j];
            oh[j] = hi;
            ol[j] = (_Float16)(f[j] - (float)hi);
        }
        *(f16x4*)&xh[(size_t)row * HH + idx * 4] = oh;
        *(f16x4*)&xl[(size_t)row * HH + idx * 4] = ol;
    }
}

// ---------------------------------------------------------------------------
// Kernel 3: GEMM h = relu(xn @ W1 + b1), fp16 3-pass split for f32 accuracy.
// m97 structure: 128x128 tile, BK=32, 4 waves (2x2), 16x16x32 f16 MFMA.
// Passes per frag pair: xh*wh + xl*wh + (xh*2^-10)*wl'   (wl' = wl*2^10)
// ---------------------------------------------------------------------------
__global__ __launch_bounds__(256) void k_gemm(const _Float16* __restrict__ Ah_g,
                                              const _Float16* __restrict__ Al_g,
                                              const _Float16* __restrict__ Bh_g,
                                              const _Float16* __restrict__ Bl_g,
                                              const float* __restrict__ b1,
                                              float* __restrict__ h) {
    __shared__ _Float16 Ah[128 * 32];
    __shared__ _Float16 Al[128 * 32];
    __shared__ _Float16 Bh[128 * 32];
    __shared__ _Float16 Bl[128 * 32];

    int bn = blockIdx.x & 15;       // N/128 = 16
    int bm = blockIdx.x >> 4;       // M/128 = 128
    int t = threadIdx.x;
    int lane = t & 63;
    int w = t >> 6;
    int wr = w >> 1, wc = w & 1;    // 2x2 wave grid, 64x64 out each

    f32x4 acc[4][4];
#pragma unroll
    for (int m = 0; m < 4; ++m)
#pragma unroll
        for (int n = 0; n < 4; ++n)
            acc[m][n] = (f32x4){0.f, 0.f, 0.f, 0.f};

    const char* pAh = (const char*)Ah_g;
    const char* pAl = (const char*)Al_g;
    const char* pBh = (const char*)Bh_g;
    const char* pBl = (const char*)Bl_g;
    int srow = t >> 2;              // 0..63
    int scolb = (t & 3) * 16;       // byte offset in 64B k-chunk
    size_t a_row = (size_t)bm * 128 + srow;
    size_t b_row = (size_t)bn * 128 + srow;
    int r16 = lane & 15, ko = lane >> 4;

    for (int kt = 0; kt < HH / 32; ++kt) {
        __syncthreads();
        size_t kb = (size_t)kt * 64 + scolb;    // 32 fp16 = 64 B per row-chunk
        gload_lds16(pAh + (a_row     ) * (HH*2) + kb, (char*)Ah + t * 16);
        gload_lds16(pAh + (a_row + 64) * (HH*2) + kb, (char*)Ah + 4096 + t * 16);
        gload_lds16(pAl + (a_row     ) * (HH*2) + kb, (char*)Al + t * 16);
        gload_lds16(pAl + (a_row + 64) * (HH*2) + kb, (char*)Al + 4096 + t * 16);
        gload_lds16(pBh + (b_row     ) * (HH*2) + kb, (char*)Bh + t * 16);
        gload_lds16(pBh + (b_row + 64) * (HH*2) + kb, (char*)Bh + 4096 + t * 16);
        gload_lds16(pBl + (b_row     ) * (HH*2) + kb, (char*)Bl + t * 16);
        gload_lds16(pBl + (b_row + 64) * (HH*2) + kb, (char*)Bl + 4096 + t * 16);
        __syncthreads();

        f16x8 fah[4], fal[4], fbh[4], fbl[4];
#pragma unroll
        for (int m = 0; m < 4; ++m) {
            int ro = (wr * 64 + m * 16 + r16) * 32 + ko * 8;
            fah[m] = *(const f16x8*)&Ah[ro];
            fal[m] = *(const f16x8*)&Al[ro];
        }
#pragma unroll
        for (int n = 0; n < 4; ++n) {
            int ro = (wc * 64 + n * 16 + r16) * 32 + ko * 8;
            fbh[n] = *(const f16x8*)&Bh[ro];
            fbl[n] = *(const f16x8*)&Bl[ro];
        }
#pragma unroll
        for (int m = 0; m < 4; ++m) {
            f16x8 fas = fah[m] * (_Float16)0.0009765625f;   // xh * 2^-10 (exact shift)
#pragma unroll
            for (int n = 0; n < 4; ++n) {
                acc[m][n] = __builtin_amdgcn_mfma_f32_16x16x32_f16(fah[m], fbh[n], acc[m][n], 0, 0, 0);
                acc[m][n] = __builtin_amdgcn_mfma_f32_16x16x32_f16(fal[m], fbh[n], acc[m][n], 0, 0, 0);
                acc[m][n] = __builtin_amdgcn_mfma_f32_16x16x32_f16(fas,    fbl[n], acc[m][n], 0, 0, 0);
            }
        }
    }

    // Epilogue: h = relu(acc + b1[col]) -> f32 global
    int hi4 = lane >> 4;
#pragma unroll
    for (int n = 0; n < 4; ++n) {
        int gcol = bn * 128 + wc * 64 + n * 16 + r16;
        float b1v = b1[gcol];
#pragma unroll
        for (int m = 0; m < 4; ++m) {
            int grow0 = bm * 128 + wr * 64 + m * 16 + hi4 * 4;
#pragma unroll
            for (int i = 0; i < 4; ++i) {
                float v = acc[m][n][i] + b1v;
                h[(size_t)(grow0 + i) * HH + gcol] = fmaxf(v, 0.f);
            }
        }
    }
}

// ---------------------------------------------------------------------------
// Kernel 4: logits[M][64] = h @ W2 (f32 VALU). One wave per 8 rows, lane=expert.
// W2 rows (64 f32 = 256B) are perfectly coalesced; each wave streams W2 once
// per 8 rows -> ~1 GB L2 traffic total.
// ---------------------------------------------------------------------------
__global__ __launch_bounds__(256) void k_gemm2(const float* __restrict__ h,
                                               const float* __restrict__ W2,
                                               float* __restrict__ logits) {
    int wid = blockIdx.x * 4 + (threadIdx.x >> 6);
    int lane = threadIdx.x & 63;
    size_t row0 = (size_t)wid * 8;
    float p[8];
#pragma unroll
    for (int r = 0; r < 8; ++r) p[r] = 0.f;

    for (int k = 0; k < HH; k += 4) {
        float w0 = W2[(size_t)(k + 0) * NE + lane];
        float w1 = W2[(size_t)(k + 1) * NE + lane];
        float w2 = W2[(size_t)(k + 2) * NE + lane];
        float w3 = W2[(size_t)(k + 3) * NE + lane];
#pragma unroll
        for (int r = 0; r < 8; ++r) {
            float4 hv = *(const float4*)&h[(row0 + r) * HH + k];
            p[r] = fmaf(hv.x, w0, p[r]);
            p[r] = fmaf(hv.y, w1, p[r]);
            p[r] = fmaf(hv.z, w2, p[r]);
            p[r] = fmaf(hv.w, w3, p[r]);
        }
    }
#pragma unroll
    for (int r = 0; r < 8; ++r) logits[(row0 + r) * NE + lane] = p[r];
}

// ---------------------------------------------------------------------------
// Kernel 5: per-row softmax over 64, top-2 (jax ties: lower index first),
// renorm, outputs, expert-prob sums.
// ---------------------------------------------------------------------------
__global__ __launch_bounds__(256) void k_final(const float* __restrict__ logits,
                                               const float* __restrict__ b2,
                                               float* __restrict__ out,
                                               float* __restrict__ sums) {
    int r = blockIdx.x * 256 + threadIdx.x;
    const float* lr = logits + (size_t)r * NE;
    float l[NE];
#pragma unroll
    for (int e = 0; e < NE; e += 4) {
        float4 v = *(const float4*)&lr[e];
        float4 b = *(const float4*)&b2[e];
        l[e]     = v.x + b.x;
        l[e + 1] = v.y + b.y;
        l[e + 2] = v.z + b.z;
        l[e + 3] = v.w + b.w;
    }
    // top-2 scan, strict > keeps lowest index on ties (jax.lax.top_k semantics)
    float m1 = -1e30f, m2 = -1e30f;
    int i1 = 0, i2 = 0;
#pragma unroll
    for (int e = 0; e < NE; ++e) {
        if (l[e] > m1)      { m2 = m1; i2 = i1; m1 = l[e]; i1 = e; }
        else if (l[e] > m2) { m2 = l[e]; i2 = e; }
    }
    float ev[NE];
    float Z = 0.f;
#pragma unroll
    for (int e = 0; e < NE; ++e) { ev[e] = expf(l[e] - m1); Z += ev[e]; }

    float eb = expf(m2 - m1);
    float pa = 1.0f / (1.0f + eb);
    float pb = eb * pa;

    out[(size_t)r * 2 + 0] = (float)i1;
    out[(size_t)r * 2 + 1] = (float)i2;
    out[(size_t)2 * MM + r * 2 + 0] = pa;
    out[(size_t)2 * MM + r * 2 + 1] = pb;

    // expert mean accumulation (full softmax probs, pre-renorm)
    float invZ = 1.0f / Z;
    __shared__ float red[4][NE];
    int lane = threadIdx.x & 63, wv = threadIdx.x >> 6;
#pragma unroll
    for (int e = 0; e < NE; ++e) {
        float q = ev[e] * invZ;
#pragma unroll
        for (int sh = 1; sh < 64; sh <<= 1) q += __shfl_xor(q, sh);
        if (lane == e) red[wv][e] = q;      // all lanes hold the sum post-butterfly
    }
    __syncthreads();
    if (threadIdx.x < NE) {
        float tot = red[0][threadIdx.x] + red[1][threadIdx.x]
                  + red[2][threadIdx.x] + red[3][threadIdx.x];
        atomicAdd(&sums[threadIdx.x], tot);
    }
}

// ---------------------------------------------------------------------------
// Kernel 6: aux loss
// ---------------------------------------------------------------------------
__global__ void k_aux(const float* __restrict__ sums, float* __restrict__ out) {
    if (threadIdx.x == 0) {
        float loss = 0.f;
        for (int e = 0; e < NE; ++e) {
            float p = sums[e] * (1.0f / MM);
            loss += p * logf(p * (float)NE + AUX_EPS);
        }
        out[(size_t)4 * MM] = loss;   // index 65536
    }
}

// ---------------------------------------------------------------------------
extern "C" void kernel_launch(void* const* d_in, const int* in_sizes, int n_in,
                              void* d_out, int out_size, void* d_ws, size_t ws_size,
                              hipStream_t stream) {
    const float* x     = (const float*)d_in[0];
    const float* W1    = (const float*)d_in[1];
    const float* b1    = (const float*)d_in[2];
    const float* W2    = (const float*)d_in[3];
    const float* b2    = (const float*)d_in[4];
    const float* gamma = (const float*)d_in[5];
    const float* beta  = (const float*)d_in[6];
    float* out = (float*)d_out;

    char* ws = (char*)d_ws;
    _Float16* xh = (_Float16*)(ws);                          //  67,108,864 B
    _Float16* xl = (_Float16*)(ws + 67108864);               //  67,108,864 B
    _Float16* Wh = (_Float16*)(ws + 134217728);              //   8,388,608 B
    _Float16* Wl = (_Float16*)(ws + 142606336);              //   8,388,608 B
    float*    h  = (float*)   (ws + 150994944);              // 134,217,728 B
    float*    lg = (float*)   (ws + 285212672);              //   4,194,304 B
    float*    sums = (float*) (ws + 289406976);              //         256 B

    hipMemsetAsync(sums, 0, NE * sizeof(float), stream);
    k_tw1  <<<4096,     256, 0, stream>>>(W1, Wh, Wl);
    k_ln   <<<MM,       256, 0, stream>>>(x, gamma, beta, xh, xl);
    k_gemm <<<2048,     256, 0, stream>>>(xh, xl, Wh, Wl, b1, h);
    k_gemm2<<<MM/32,    256, 0, stream>>>(h, W2, lg);
    k_final<<<MM/256,   256, 0, stream>>>(lg, b2, out, sums);
    k_aux  <<<1, 64, 0, stream>>>(sums, out);
}